// Round 8
// baseline (1047.988 us; speedup 1.0000x reference)
//
#include <hip/hip_runtime.h>
#include <hip/hip_bf16.h>
#include <hip/hip_fp16.h>

// GCN: 4 layers. N=100000, E=1600000, F=H=128, C=40. fp32 in/out.
// R13 changes vs R12:
//  - Degree-sorted node permutation (counting sort, 64 buckets): fused
//    blocks process 16 equal-degree nodes -> barrier straggler ~0
//    (R12: fused 75us vs standalone-agg 62us at SAME fetch; gap = max-of-4
//    wave imbalance). Per-node summation order unchanged -> same absmax.
//  - CSR cells packed int2 -> int ((ldst<<25)|src): pass1 write 25.6->12.8MB,
//    count/pass2 reads halved.

#define N_NODES 100000
#define N_EDGES 1600000

#define BSHIFT 7
#define BWIDTH 128
#define CELL_CAP 512
#define P1_EPT 16
#define P1_CHUNK 4096

typedef short s16x8 __attribute__((ext_vector_type(8)));
typedef _Float16 f16x8 __attribute__((ext_vector_type(8)));
typedef float f32x4 __attribute__((ext_vector_type(4)));
typedef float f32x2 __attribute__((ext_vector_type(2)));

// ---------------- CSR build (bucketed, packed cells) ----------------

__global__ __launch_bounds__(256) void pass1_bucket(const int* __restrict__ src,
                                                    const int* __restrict__ dst,
                                                    int* __restrict__ bcur2,
                                                    unsigned* __restrict__ cells,
                                                    int2* __restrict__ spill,
                                                    int* __restrict__ spillCnt,
                                                    int nb, int e) {
    __shared__ int hist[1024];
    __shared__ int base[1024];
    int t = threadIdx.x;
    int x = blockIdx.x & 7;
    int e0 = blockIdx.x * P1_CHUNK;

    for (int i = t; i < nb; i += 256) hist[i] = 0;
    __syncthreads();

    int ds[P1_EPT], ss[P1_EPT];
#pragma unroll
    for (int j = 0; j < P1_EPT; j++) {
        int i = e0 + j * 256 + t;
        if (i < e) {
            ds[j] = dst[i];
            ss[j] = src[i];
            atomicAdd(&hist[ds[j] >> BSHIFT], 1);
        } else {
            ds[j] = -1;
        }
    }
    __syncthreads();

    for (int i = t; i < nb; i += 256) {
        int h = hist[i];
        base[i] = (h > 0) ? atomicAdd(&bcur2[i * 8 + x], h) : 0;
        hist[i] = 0;
    }
    __syncthreads();

#pragma unroll
    for (int j = 0; j < P1_EPT; j++) {
        if (ds[j] >= 0) {
            int b = ds[j] >> BSHIFT;
            int r = atomicAdd(&hist[b], 1);
            int slot = base[b] + r;
            if (slot < CELL_CAP) {
                cells[(size_t)(b * 8 + x) * CELL_CAP + slot] =
                    ((unsigned)(ds[j] & (BWIDTH - 1)) << 25) | (unsigned)ss[j];
            } else {
                int sp = atomicAdd(spillCnt, 1);
                spill[sp] = make_int2(ss[j], ds[j]);
            }
        }
    }
}

__global__ __launch_bounds__(256) void count_cells(const int* __restrict__ bcur2,
                                                   const unsigned* __restrict__ cells,
                                                   const int2* __restrict__ spill,
                                                   const int* __restrict__ spillCnt,
                                                   int* __restrict__ counts,
                                                   float* __restrict__ dinv,
                                                   int n) {
    __shared__ int cnt[BWIDTH];
    int b = blockIdx.x;
    int t = threadIdx.x;
    int nodeBase = b << BSHIFT;
    if (t < BWIDTH) cnt[t] = 0;
    __syncthreads();
    for (int x = 0; x < 8; x++) {
        int c = bcur2[b * 8 + x];
        if (c > CELL_CAP) c = CELL_CAP;
        const unsigned* cp = cells + (size_t)(b * 8 + x) * CELL_CAP;
        for (int s = t; s < c; s += 256) {
            atomicAdd(&cnt[cp[s] >> 25], 1);
        }
    }
    int sc = *spillCnt;
    for (int s = t; s < sc; s += 256) {
        int d = spill[s].y;
        if ((d >> BSHIFT) == b) atomicAdd(&cnt[d - nodeBase], 1);
    }
    __syncthreads();
    if (t < BWIDTH) {
        int node = nodeBase + t;
        if (node < n) {
            int deg = cnt[t] + 1;
            counts[node] = deg;
            dinv[node] = 1.0f / sqrtf((float)deg);
        }
    }
}

__global__ __launch_bounds__(256) void scan_phase1(const int* __restrict__ counts,
                                                   int* __restrict__ blockSums, int n) {
    __shared__ int red[256];
    int t = threadIdx.x;
    int base = blockIdx.x * 1024 + t * 4;
    int s = 0;
    if (base + 3 < n) {
        int4 v = *(const int4*)(counts + base);
        s = ((v.x + 2) & ~3) + ((v.y + 2) & ~3) + ((v.z + 2) & ~3) + ((v.w + 2) & ~3);
    } else {
        for (int j = 0; j < 4; j++) if (base + j < n) s += (counts[base + j] + 2) & ~3;
    }
    red[t] = s;
    __syncthreads();
    for (int off = 128; off > 0; off >>= 1) {
        if (t < off) red[t] += red[t + off];
        __syncthreads();
    }
    if (t == 0) blockSums[blockIdx.x] = red[0];
}

__global__ __launch_bounds__(1024) void scan_phase2(int* __restrict__ blockSums, int nb) {
    __shared__ int sh[1024];
    int t = threadIdx.x;
    sh[t] = (t < nb) ? blockSums[t] : 0;
    __syncthreads();
    for (int off = 1; off < 1024; off <<= 1) {
        int v = (t >= off) ? sh[t - off] : 0;
        __syncthreads();
        sh[t] += v;
        __syncthreads();
    }
    if (t < nb) blockSums[t] = (t == 0) ? 0 : sh[t - 1];
}

__global__ __launch_bounds__(256) void scan_phase3(const int* __restrict__ counts,
                                                   const int* __restrict__ blockSums,
                                                   int* __restrict__ offsets, int n) {
    __shared__ int red[256];
    int t = threadIdx.x;
    int base = blockIdx.x * 1024 + t * 4;
    int c[4];
#pragma unroll
    for (int j = 0; j < 4; j++) c[j] = (base + j < n) ? ((counts[base + j] + 2) & ~3) : 0;
    int s = c[0] + c[1] + c[2] + c[3];
    red[t] = s;
    __syncthreads();
    for (int off = 1; off < 256; off <<= 1) {
        int v = (t >= off) ? red[t - off] : 0;
        __syncthreads();
        red[t] += v;
        __syncthreads();
    }
    int prefix = blockSums[blockIdx.x] + ((t == 0) ? 0 : red[t - 1]);
#pragma unroll
    for (int j = 0; j < 4; j++) {
        if (base + j < n) offsets[base + j] = prefix;
        prefix += c[j];
        if (base + j == n - 1) offsets[n] = prefix;
    }
}

__global__ __launch_bounds__(256) void pass2_scatter(const int* __restrict__ bcur2,
                                                     const unsigned* __restrict__ cells,
                                                     const int2* __restrict__ spill,
                                                     const int* __restrict__ spillCnt,
                                                     const int* __restrict__ offsets,
                                                     int* __restrict__ srcSorted, int n) {
    __shared__ int cur[BWIDTH];
    int b = blockIdx.x;
    int t = threadIdx.x;
    int nodeBase = b << BSHIFT;
    if (t < BWIDTH) cur[t] = 0;
    __syncthreads();
    for (int x = 0; x < 8; x++) {
        int c = bcur2[b * 8 + x];
        if (c > CELL_CAP) c = CELL_CAP;
        const unsigned* cp = cells + (size_t)(b * 8 + x) * CELL_CAP;
        for (int s = t; s < c; s += 256) {
            unsigned v = cp[s];
            int l = (int)(v >> 25);
            int r = atomicAdd(&cur[l], 1);
            srcSorted[offsets[nodeBase + l] + r] = (int)(v & 0x1FFFFFFu);
        }
    }
    int sc = *spillCnt;
    for (int s = t; s < sc; s += 256) {
        int2 p = spill[s];
        if ((p.y >> BSHIFT) == b) {
            int r = atomicAdd(&cur[p.y - nodeBase], 1);
            srcSorted[offsets[p.y] + r] = p.x;
        }
    }
    __syncthreads();
    if (t < BWIDTH) {
        int node = nodeBase + t;
        if (node < n) {
            int beg = offsets[node] + cur[t];
            int end = offsets[node + 1];
            for (int k = beg; k < end; k++) srcSorted[k] = n;
        }
    }
}

// ---------------- degree-sorted permutation ----------------

__global__ void sort_hist(const int* __restrict__ counts, int* __restrict__ hist, int n) {
    __shared__ int lh[64];
    int t = threadIdx.x;
    if (t < 64) lh[t] = 0;
    __syncthreads();
    int i = blockIdx.x * 256 + t;
    if (i < n) {
        int b = (counts[i] + 2) >> 2; if (b > 63) b = 63;
        atomicAdd(&lh[b], 1);
    }
    __syncthreads();
    if (t < 64 && lh[t] > 0) atomicAdd(&hist[t], lh[t]);
}

__global__ void sort_scan64(int* __restrict__ hist) {
    if (threadIdx.x == 0 && blockIdx.x == 0) {
        int acc = 0;
        for (int i = 0; i < 64; i++) { int v = hist[i]; hist[i] = acc; acc += v; }
    }
}

__global__ void sort_scatter(const int* __restrict__ counts, int* __restrict__ hist,
                             int* __restrict__ perm, int n) {
    int i = blockIdx.x * blockDim.x + threadIdx.x;
    if (i < n) {
        int b = (counts[i] + 2) >> 2; if (b > 63) b = 63;
        int pos = atomicAdd(&hist[b], 1);
        perm[pos] = i;
    }
}

// ---------------- weight prep ----------------

__device__ inline void split_bf16(float f, unsigned short& h, unsigned short& l) {
    unsigned u = __float_as_uint(f);
    unsigned hr = (u + 0x7FFFu + ((u >> 16) & 1u)) >> 16;
    h = (unsigned short)hr;
    float r = f - __uint_as_float(hr << 16);
    unsigned v = __float_as_uint(r);
    unsigned lr = (v + 0x7FFFu + ((v >> 16) & 1u)) >> 16;
    l = (unsigned short)lr;
}

__global__ __launch_bounds__(256) void prep_wfrag(const float* __restrict__ W,
                                                  short* __restrict__ wh,
                                                  short* __restrict__ wl,
                                                  __half* __restrict__ zrow) {
    if (zrow != nullptr && blockIdx.x == 0 && threadIdx.x < 64) {
        ((__half2*)zrow)[threadIdx.x] = __floats2half2_rn(0.f, 0.f);
    }
    int idx = blockIdx.x * 256 + threadIdx.x;
    int j    = idx & 7;
    int lane = (idx >> 3) & 63;
    int c    = (idx >> 9) & 3;
    int t    = idx >> 11;
    int quad = lane >> 4;
    int n = (t << 4) | (lane & 15);
    int k = (c << 5) + (quad << 3) + j;
    unsigned short h, l;
    split_bf16(W[k * 128 + n], h, l);
    wh[idx] = (short)h;
    wl[idx] = (short)l;
}

__global__ __launch_bounds__(256) void prep_wfrag16(const float* __restrict__ W,
                                                    _Float16* __restrict__ wh,
                                                    _Float16* __restrict__ wl,
                                                    __half* __restrict__ zrow) {
    if (zrow != nullptr && blockIdx.x == 0 && threadIdx.x < 64) {
        ((__half2*)zrow)[threadIdx.x] = __floats2half2_rn(0.f, 0.f);
    }
    int idx = blockIdx.x * 256 + threadIdx.x;
    int j    = idx & 7;
    int lane = (idx >> 3) & 63;
    int c    = (idx >> 9) & 3;
    int t    = idx >> 11;
    int quad = lane >> 4;
    int n = (t << 4) | (lane & 15);
    int k = (c << 5) + (quad << 3) + j;
    float v = W[k * 128 + n];
    _Float16 h = (_Float16)v;
    _Float16 l = (_Float16)((v - (float)h) * 2048.0f);
    wh[idx] = h;
    wl[idx] = l;
}

__global__ __launch_bounds__(256) void prep_wfrag40(const float* __restrict__ W,
                                                    _Float16* __restrict__ wh,
                                                    _Float16* __restrict__ wl) {
    int idx = blockIdx.x * 256 + threadIdx.x;   // 0..6143
    int j    = idx & 7;
    int lane = (idx >> 3) & 63;
    int c    = (idx >> 9) & 3;
    int t    = idx >> 11;                        // 0..2
    int quad = lane >> 4;
    int n = (t << 4) | (lane & 15);              // 0..47
    int k = (c << 5) + (quad << 3) + j;
    float v = (n < 40) ? W[k * 40 + n] : 0.f;
    _Float16 h = (_Float16)v;
    _Float16 l = (_Float16)((v - (float)h) * 2048.0f);
    wh[idx] = h;
    wl[idx] = l;
}

// ---------------- GEMM layer 1: fp32 A, bf16-split MFMA -> h1' fp16 --------

#define GEMM_GX 512

__global__ __launch_bounds__(256) void gemm_mfma(const float* __restrict__ A,
                                                 const short* __restrict__ wh,
                                                 const short* __restrict__ wl,
                                                 const float* __restrict__ dinv,
                                                 __half* __restrict__ C, int M) {
    int wv   = threadIdx.x >> 6;
    int lane = threadIdx.x & 63;
    int quad = lane >> 4;
    int mm   = lane & 15;
    int tbase = blockIdx.y * 4;

    s16x8 whf[4][4], wlf[4][4];
#pragma unroll
    for (int tt = 0; tt < 4; tt++)
#pragma unroll
        for (int c = 0; c < 4; c++) {
            int base = ((((tbase + tt) << 2) + c) << 6 | lane) << 3;
            whf[tt][c] = *(const s16x8*)(wh + base);
            wlf[tt][c] = *(const s16x8*)(wl + base);
        }

    int nStrips = M >> 4;
    for (int s = blockIdx.x * 4 + wv; s < nStrips; s += GEMM_GX * 4) {
        const float* ap = A + (size_t)((s << 4) + mm) * 128 + (quad << 3);
        f32x4 acc[4];
#pragma unroll
        for (int tt = 0; tt < 4; tt++) acc[tt] = (f32x4){0.f, 0.f, 0.f, 0.f};

#pragma unroll
        for (int c = 0; c < 4; c++) {
            float av[8];
            *(float4*)&av[0] = *(const float4*)(ap + (c << 5));
            *(float4*)&av[4] = *(const float4*)(ap + (c << 5) + 4);
            union { s16x8 v; unsigned short u[8]; } ah, al;
#pragma unroll
            for (int j = 0; j < 8; j++) split_bf16(av[j], ah.u[j], al.u[j]);
#pragma unroll
            for (int tt = 0; tt < 4; tt++) {
                acc[tt] = __builtin_amdgcn_mfma_f32_16x16x32_bf16(ah.v, whf[tt][c], acc[tt], 0, 0, 0);
                acc[tt] = __builtin_amdgcn_mfma_f32_16x16x32_bf16(ah.v, wlf[tt][c], acc[tt], 0, 0, 0);
                acc[tt] = __builtin_amdgcn_mfma_f32_16x16x32_bf16(al.v, whf[tt][c], acc[tt], 0, 0, 0);
                acc[tt] = __builtin_amdgcn_mfma_f32_16x16x32_bf16(al.v, wlf[tt][c], acc[tt], 0, 0, 0);
            }
        }
        int rbase = (s << 4) + (quad << 2);
        float dv[4];
#pragma unroll
        for (int r = 0; r < 4; r++) dv[r] = dinv[rbase + r];
        __half* cp = C + (size_t)rbase * 128 + (tbase << 4) + mm;
#pragma unroll
        for (int tt = 0; tt < 4; tt++) {
#pragma unroll
            for (int r = 0; r < 4; r++) {
                cp[(size_t)r * 128 + (tt << 4)] = __float2half(acc[tt][r] * dv[r]);
            }
        }
    }
}

// ---------------- fused agg + gemm (degree-sorted perm) ----------------

__device__ inline f32x2 h2f(__half2 v) {
    float2 t = __half22float2(v);
    return (f32x2){t.x, t.y};
}

#define GATHER_NODE(IDX, END)                                                   \
    {                                                                           \
        int4 sA, sB;                                                            \
        bool have8 = (IDX + 8 <= END);                                          \
        if (have8) {                                                            \
            sA = *(const int4*)(srcSorted + IDX);                               \
            sB = *(const int4*)(srcSorted + IDX + 4);                           \
        }                                                                       \
        while (have8) {                                                         \
            int4 cA = sA, cB = sB;                                              \
            int nidx = IDX + 8;                                                 \
            bool nxt = (nidx + 8 <= END);                                       \
            if (nxt) {                                                          \
                sA = *(const int4*)(srcSorted + nidx);                          \
                sB = *(const int4*)(srcSorted + nidx + 4);                      \
            }                                                                   \
            __half2 v0 = *(const __half2*)(hb + (unsigned)cA.x * 256u + fb);    \
            __half2 v1 = *(const __half2*)(hb + (unsigned)cA.y * 256u + fb);    \
            __half2 v2 = *(const __half2*)(hb + (unsigned)cA.z * 256u + fb);    \
            __half2 v3 = *(const __half2*)(hb + (unsigned)cA.w * 256u + fb);    \
            __half2 v4 = *(const __half2*)(hb + (unsigned)cB.x * 256u + fb);    \
            __half2 v5 = *(const __half2*)(hb + (unsigned)cB.y * 256u + fb);    \
            __half2 v6 = *(const __half2*)(hb + (unsigned)cB.z * 256u + fb);    \
            __half2 v7 = *(const __half2*)(hb + (unsigned)cB.w * 256u + fb);    \
            a0 += h2f(v0); a1 += h2f(v1); a2 += h2f(v2); a3 += h2f(v3);         \
            a0 += h2f(v4); a1 += h2f(v5); a2 += h2f(v6); a3 += h2f(v7);         \
            IDX = nidx;                                                         \
            have8 = nxt;                                                        \
        }                                                                       \
        if (IDX + 4 <= END) {                                                   \
            int4 cA = *(const int4*)(srcSorted + IDX);                          \
            __half2 v0 = *(const __half2*)(hb + (unsigned)cA.x * 256u + fb);    \
            __half2 v1 = *(const __half2*)(hb + (unsigned)cA.y * 256u + fb);    \
            __half2 v2 = *(const __half2*)(hb + (unsigned)cA.z * 256u + fb);    \
            __half2 v3 = *(const __half2*)(hb + (unsigned)cA.w * 256u + fb);    \
            a0 += h2f(v0); a1 += h2f(v1); a2 += h2f(v2); a3 += h2f(v3);         \
        }                                                                       \
    }

__global__ __launch_bounds__(256) void fused_agg_gemm128(const __half* __restrict__ hsrc,
                                                         const _Float16* __restrict__ wh,
                                                         const _Float16* __restrict__ wl,
                                                         const float* __restrict__ dinv,
                                                         const int* __restrict__ offsets,
                                                         const int* __restrict__ srcSorted,
                                                         const int* __restrict__ perm,
                                                         const float* __restrict__ bias,
                                                         __half* __restrict__ hdst, int n) {
    __shared__ __align__(16) _Float16 aST[16 * 136];
    int wave = threadIdx.x >> 6;
    int lane = threadIdx.x & 63;
    int strip = blockIdx.x;
    int f = lane * 2;
    unsigned fb = (unsigned)f * 2u;
    const char* hb = (const char*)hsrc;
    float2 bv = *(const float2*)(bias + f);

    for (int i = 0; i < 4; i++) {
        int row = (wave << 2) + i;
        int k = (strip << 4) + row;
        bool on = (k < n);
        int node = on ? perm[k] : 0;
        float di = on ? dinv[node] : 0.f;
        int idx = on ? offsets[node] : 0;
        int end = on ? offsets[node + 1] : 0;

        f32x2 z = (f32x2){0.f, 0.f};
        f32x2 a0 = z, a1 = z, a2 = z, a3 = z;
        if (on) a0 = h2f(*(const __half2*)(hb + (unsigned)node * 256u + fb));
        GATHER_NODE(idx, end);

        f32x2 s = (a0 + a1) + (a2 + a3);
        float ox = fmaxf(di * s.x + bv.x, 0.f);
        float oy = fmaxf(di * s.y + bv.y, 0.f);
        *(__half2*)(aST + row * 136 + f) = __floats2half2_rn(ox, oy);
    }
    __syncthreads();

    int quad = lane >> 4;
    int mm   = lane & 15;
    f16x8 av[4];
#pragma unroll
    for (int c = 0; c < 4; c++)
        av[c] = *(const f16x8*)(aST + mm * 136 + (c << 5) + (quad << 3));
    int kb = (strip << 4) + (quad << 2);
    int nd[4]; float dv[4];
#pragma unroll
    for (int r = 0; r < 4; r++) {
        bool v = (kb + r < n);
        nd[r] = v ? perm[kb + r] : 0;
        dv[r] = v ? dinv[nd[r]] : 0.f;
    }

#pragma unroll
    for (int t2 = 0; t2 < 2; t2++) {
        int gt = (wave << 1) + t2;
        f32x4 acch = (f32x4){0.f, 0.f, 0.f, 0.f};
        f32x4 accl = (f32x4){0.f, 0.f, 0.f, 0.f};
#pragma unroll
        for (int c = 0; c < 4; c++) {
            int base = (((gt << 2) + c) << 6 | lane) << 3;
            f16x8 bh = *(const f16x8*)(wh + base);
            f16x8 bl = *(const f16x8*)(wl + base);
            acch = __builtin_amdgcn_mfma_f32_16x16x32_f16(av[c], bh, acch, 0, 0, 0);
            accl = __builtin_amdgcn_mfma_f32_16x16x32_f16(av[c], bl, accl, 0, 0, 0);
        }
#pragma unroll
        for (int r = 0; r < 4; r++) {
            if (kb + r < n) {
                float v = acch[r] + accl[r] * (1.0f / 2048.0f);
                hdst[(size_t)nd[r] * 128 + (gt << 4) + mm] = __float2half(v * dv[r]);
            }
        }
    }
}

__global__ __launch_bounds__(256) void fused_agg_gemm40(const __half* __restrict__ hsrc,
                                                        const _Float16* __restrict__ wh,
                                                        const _Float16* __restrict__ wl,
                                                        const float* __restrict__ dinv,
                                                        const int* __restrict__ offsets,
                                                        const int* __restrict__ srcSorted,
                                                        const int* __restrict__ perm,
                                                        const float* __restrict__ bias,
                                                        float* __restrict__ xlat,
                                                        __half* __restrict__ hdst, int n) {
    __shared__ __align__(16) _Float16 aST[16 * 136];
    int wave = threadIdx.x >> 6;
    int lane = threadIdx.x & 63;
    int strip = blockIdx.x;
    int f = lane * 2;
    unsigned fb = (unsigned)f * 2u;
    const char* hb = (const char*)hsrc;
    float2 bv = *(const float2*)(bias + f);

    if (blockIdx.x == 0 && threadIdx.x < 20) {   // zero h4' dummy row n
        ((__half2*)(hdst + (size_t)n * 40))[threadIdx.x] = __floats2half2_rn(0.f, 0.f);
    }

    int ndg[4];
    for (int i = 0; i < 4; i++) {
        int row = (wave << 2) + i;
        int k = (strip << 4) + row;
        bool on = (k < n);
        int node = on ? perm[k] : 0;
        ndg[i] = node;
        float di = on ? dinv[node] : 0.f;
        int idx = on ? offsets[node] : 0;
        int end = on ? offsets[node + 1] : 0;

        f32x2 z = (f32x2){0.f, 0.f};
        f32x2 a0 = z, a1 = z, a2 = z, a3 = z;
        if (on) a0 = h2f(*(const __half2*)(hb + (unsigned)node * 256u + fb));
        GATHER_NODE(idx, end);

        f32x2 s = (a0 + a1) + (a2 + a3);
        float ox = fmaxf(di * s.x + bv.x, 0.f);
        float oy = fmaxf(di * s.y + bv.y, 0.f);
        if (on) *(float2*)(xlat + (size_t)node * 128 + f) = make_float2(ox, oy);
        *(__half2*)(aST + row * 136 + f) = __floats2half2_rn(ox, oy);
    }
    __syncthreads();

    if (wave < 3) {
        int quad = lane >> 4;
        int mm   = lane & 15;
        f16x8 av[4];
#pragma unroll
        for (int c = 0; c < 4; c++)
            av[c] = *(const f16x8*)(aST + mm * 136 + (c << 5) + (quad << 3));
        int kb = (strip << 4) + (quad << 2);
        int nd[4]; float dv[4];
#pragma unroll
        for (int r = 0; r < 4; r++) {
            bool v = (kb + r < n);
            nd[r] = v ? perm[kb + r] : 0;
            dv[r] = v ? dinv[nd[r]] : 0.f;
        }

        int gt = wave;
        f32x4 acch = (f32x4){0.f, 0.f, 0.f, 0.f};
        f32x4 accl = (f32x4){0.f, 0.f, 0.f, 0.f};
#pragma unroll
        for (int c = 0; c < 4; c++) {
            int base = (((gt << 2) + c) << 6 | lane) << 3;
            f16x8 bh = *(const f16x8*)(wh + base);
            f16x8 bl = *(const f16x8*)(wl + base);
            acch = __builtin_amdgcn_mfma_f32_16x16x32_f16(av[c], bh, acch, 0, 0, 0);
            accl = __builtin_amdgcn_mfma_f32_16x16x32_f16(av[c], bl, accl, 0, 0, 0);
        }
        int col = (gt << 4) + mm;
#pragma unroll
        for (int r = 0; r < 4; r++) {
            if (kb + r < n && col < 40) {
                float v = acch[r] + accl[r] * (1.0f / 2048.0f);
                hdst[(size_t)nd[r] * 40 + col] = __float2half(v * dv[r]);
            }
        }
    }
}

// NF=40 final agg: three nodes per wave, fp32 out, no relu.
__global__ __launch_bounds__(256) void agg40_tri(const __half* __restrict__ h,
                                                 const float* __restrict__ dinv,
                                                 const int* __restrict__ offsets,
                                                 const int* __restrict__ srcSorted,
                                                 const float* __restrict__ bias,
                                                 float* __restrict__ out, int n) {
    int wave = threadIdx.x >> 6;
    int lane = threadIdx.x & 63;
    unsigned sub = (unsigned)lane / 20u;
    int fi = lane - (int)sub * 20;
    bool act = (sub < 3u);
    int f = fi * 2;
    unsigned fb = (unsigned)fi * 4u;
    const char* hb = (const char*)h;
    float bx = act ? bias[f] : 0.f;
    float by = act ? bias[f + 1] : 0.f;
    int ntri = (n + 2) / 3;

    for (int p = blockIdx.x * 4 + wave; p < ntri; p += gridDim.x * 4) {
        int node = p * 3 + (int)sub;
        bool on = act && (node < n);
        float di = on ? dinv[node] : 0.f;
        int idx = on ? offsets[node] : 0;
        int end = on ? offsets[node + 1] : 0;

        f32x2 z = (f32x2){0.f, 0.f};
        f32x2 a0 = z, a1 = z, a2 = z, a3 = z;
        if (on) a0 = h2f(*(const __half2*)(hb + (unsigned)node * 80u + fb));

        while (__any(idx + 8 <= end)) {
            bool c = (idx + 8 <= end);
            if (c) {
                int4 sA = *(const int4*)(srcSorted + idx);
                int4 sB = *(const int4*)(srcSorted + idx + 4);
                a0 += h2f(*(const __half2*)(hb + (unsigned)sA.x * 80u + fb));
                a1 += h2f(*(const __half2*)(hb + (unsigned)sA.y * 80u + fb));
                a2 += h2f(*(const __half2*)(hb + (unsigned)sA.z * 80u + fb));
                a3 += h2f(*(const __half2*)(hb + (unsigned)sA.w * 80u + fb));
                a0 += h2f(*(const __half2*)(hb + (unsigned)sB.x * 80u + fb));
                a1 += h2f(*(const __half2*)(hb + (unsigned)sB.y * 80u + fb));
                a2 += h2f(*(const __half2*)(hb + (unsigned)sB.z * 80u + fb));
                a3 += h2f(*(const __half2*)(hb + (unsigned)sB.w * 80u + fb));
                idx += 8;
            }
        }
        if (idx + 4 <= end) {
            int4 sA = *(const int4*)(srcSorted + idx);
            a0 += h2f(*(const __half2*)(hb + (unsigned)sA.x * 80u + fb));
            a1 += h2f(*(const __half2*)(hb + (unsigned)sA.y * 80u + fb));
            a2 += h2f(*(const __half2*)(hb + (unsigned)sA.z * 80u + fb));
            a3 += h2f(*(const __half2*)(hb + (unsigned)sA.w * 80u + fb));
        }

        if (on) {
            f32x2 s = (a0 + a1) + (a2 + a3);
            float ox = di * s.x + bx;
            float oy = di * s.y + by;
            *(float2*)(out + (size_t)node * 40 + f) = make_float2(ox, oy);
        }
    }
}

// ---------------- orchestration ----------------

extern "C" void kernel_launch(void* const* d_in, const int* in_sizes, int n_in,
                              void* d_out, int out_size, void* d_ws, size_t ws_size,
                              hipStream_t stream) {
    const float* x  = (const float*)d_in[0];
    const int* edge = (const int*)d_in[1];
    const float* W1 = (const float*)d_in[2]; const float* b1 = (const float*)d_in[3];
    const float* W2 = (const float*)d_in[4]; const float* b2 = (const float*)d_in[5];
    const float* W3 = (const float*)d_in[6]; const float* b3 = (const float*)d_in[7];
    const float* W4 = (const float*)d_in[8]; const float* b4 = (const float*)d_in[9];

    const int N = in_sizes[0] / 128;      // 100000
    const int E = in_sizes[1] / 2;        // 1600000
    const int* src = edge;
    const int* dst = edge + E;

    float* out_final = (float*)d_out;                    // [N,40]
    float* x_latent  = (float*)d_out + (size_t)N * 40;   // [N,128]

    const int nbk = (N + BWIDTH - 1) >> BSHIFT;          // 782

    // workspace carve-up
    char* w = (char*)d_ws;
    int* counts    = (int*)w;  w += (size_t)N * 4;
    int* offsets   = (int*)w;  w += (size_t)(N + 4) * 4;
    float* dinv    = (float*)w; w += (size_t)N * 4;
    int* perm      = (int*)w;  w += (size_t)N * 4;
    int* srcSorted = (int*)w;  w += (size_t)(E + 4 * N) * 4;
    int* blockSums = (int*)w;  w += (size_t)1024 * 4;
    int* bcur2     = (int*)w;  w += (size_t)8448 * 4;
    int* spillCnt  = (int*)w;  w += (size_t)64 * 4;
    int* sortHist  = (int*)w;  w += (size_t)128 * 4;     // contiguous with bcur2 for memset
    short* wfrag   = (short*)w;    w += (size_t)2 * 16384 * 2;   // W1 {hi,lo} bf16
    _Float16* wf16 = (_Float16*)w; w += (size_t)4 * 16384 * 2;   // W2,W3 {hi,lo} f16
    _Float16* wf40 = (_Float16*)w; w += (size_t)2 * 6144 * 2;    // W4 {hi,lo} f16 48-col
    w = (char*)(((uintptr_t)w + 255) & ~(uintptr_t)255);
    __half* hA   = (__half*)w; w += (size_t)(N + 1) * 128 * 2;   // h-tables ping
    __half* hB16 = (__half*)w; w += (size_t)(N + 1) * 128 * 2;   // h-tables pong

    // cells (packed int, 12.8MB) + spill (int2, 12.8MB) alias hA region
    unsigned* cells = (unsigned*)hA;
    int2* spill = (int2*)(cells + (size_t)nbk * 8 * CELL_CAP);

    short* wh1 = wfrag;            short* wl1 = wfrag + 16384;
    _Float16* wh2 = wf16;          _Float16* wl2 = wf16 + 16384;
    _Float16* wh3 = wf16 + 32768;  _Float16* wl3 = wf16 + 49152;
    _Float16* wh4 = wf40;          _Float16* wl4 = wf40 + 6144;

    int gN = (N + 255) / 256;
    int nb = (N + 1023) / 1024;
    int p1b = (E + P1_CHUNK - 1) / P1_CHUNK;
    int nStrips = (N + 15) / 16;   // 6250

    hipMemsetAsync(bcur2, 0, (size_t)(8448 + 64 + 128) * 4, stream);  // bcur2+spillCnt+sortHist
    pass1_bucket<<<p1b, 256, 0, stream>>>(src, dst, bcur2, cells, spill, spillCnt, nbk, E);
    count_cells<<<nbk, 256, 0, stream>>>(bcur2, cells, spill, spillCnt, counts, dinv, N);
    scan_phase1<<<nb, 256, 0, stream>>>(counts, blockSums, N);
    scan_phase2<<<1, 1024, 0, stream>>>(blockSums, nb);
    scan_phase3<<<nb, 256, 0, stream>>>(counts, blockSums, offsets, N);
    pass2_scatter<<<nbk, 256, 0, stream>>>(bcur2, cells, spill, spillCnt, offsets, srcSorted, N);
    sort_hist<<<gN, 256, 0, stream>>>(counts, sortHist, N);
    sort_scan64<<<1, 64, 0, stream>>>(sortHist);
    sort_scatter<<<gN, 256, 0, stream>>>(counts, sortHist, perm, N);

    prep_wfrag<<<64, 256, 0, stream>>>(W1, wh1, wl1, hA + (size_t)N * 128);
    prep_wfrag16<<<64, 256, 0, stream>>>(W2, wh2, wl2, hB16 + (size_t)N * 128);
    prep_wfrag16<<<64, 256, 0, stream>>>(W3, wh3, wl3, nullptr);
    prep_wfrag40<<<24, 256, 0, stream>>>(W4, wh4, wl4);

    dim3 gGemm(GEMM_GX, 2);

    gemm_mfma<<<gGemm, 256, 0, stream>>>(x, wh1, wl1, dinv, hA, N);                 // h1' -> hA
    fused_agg_gemm128<<<nStrips, 256, 0, stream>>>(hA, wh2, wl2, dinv, offsets,
                                                   srcSorted, perm, b1, hB16, N);   // h2' -> hB16
    fused_agg_gemm128<<<nStrips, 256, 0, stream>>>(hB16, wh3, wl3, dinv, offsets,
                                                   srcSorted, perm, b2, hA, N);     // h3' -> hA
    fused_agg_gemm40<<<nStrips, 256, 0, stream>>>(hA, wh4, wl4, dinv, offsets,
                                                  srcSorted, perm, b3, x_latent, hB16, N);
    agg40_tri<<<2048, 256, 0, stream>>>(hB16, dinv, offsets, srcSorted, b4, out_final, N);
}